// Round 1
// baseline (150.365 us; speedup 1.0000x reference)
//
#include <hip/hip_runtime.h>

// DSBatchNorm: per-domain batch stats + affine. N=16384 rows, F=1024 feats, D=8 domains.
// Pass 1: per-(rowgroup, domain, feature) partial s1/s2 in registers -> ws (no atomics on s1/s2).
// Pass 2: reduce partials, fold count edge cases into scale/shift.
// Pass 3: out = x*scale[y] + shift[y]  (branch-free).

#define EPSV 1e-5f
constexpr int N = 16384;
constexpr int F = 1024;
constexpr int D = 8;
constexpr int ROWS_PER_BLOCK = 128;
constexpr int RG = N / ROWS_PER_BLOCK; // 128 row-groups

// ---------------- kernel 1: partial sums ----------------
// grid = RG*2 (2 column halves), block = 256. Each thread owns 2 consecutive
// floats (float2) of one half-row. acc[8] per-domain in registers.
// y[n] address is uniform (block/loop indices only) -> s_load + uniform branch.
__global__ __launch_bounds__(256) void k1_partials(
    const float* __restrict__ x, const int* __restrict__ y,
    float* __restrict__ partials, int* __restrict__ counts) {
  const int t = threadIdx.x;
  const int rg = blockIdx.x >> 1;
  const int h = blockIdx.x & 1;

  __shared__ int hist[D];
  if (t < D) hist[t] = 0;
  __syncthreads();
  if (h == 0 && t < ROWS_PER_BLOCK) {
    int d = y[rg * ROWS_PER_BLOCK + t];
    atomicAdd(&hist[d], 1);
  }
  __syncthreads();
  if (h == 0 && t < D) atomicAdd(&counts[t], hist[t]);

  float2 a1[D], a2[D];
#pragma unroll
  for (int k = 0; k < D; ++k) {
    a1[k] = make_float2(0.f, 0.f);
    a2[k] = make_float2(0.f, 0.f);
  }

  const float2* __restrict__ x2 = (const float2*)x;
  const int col2 = h * 256 + t;  // float2 column index, 0..511
  const int row0 = rg * ROWS_PER_BLOCK;

#define ACC(K)                            \
  a1[K].x += v.x;                         \
  a1[K].y += v.y;                         \
  a2[K].x = fmaf(v.x, v.x, a2[K].x);      \
  a2[K].y = fmaf(v.y, v.y, a2[K].y);      \
  break;

  for (int r = 0; r < ROWS_PER_BLOCK; r += 8) {
    const int n = row0 + r;
    int dd[8];
    float2 vv[8];
#pragma unroll
    for (int j = 0; j < 8; ++j) dd[j] = y[n + j];        // uniform -> SGPR
#pragma unroll
    for (int j = 0; j < 8; ++j) vv[j] = x2[(n + j) * 512 + col2];  // 8 loads in flight
#pragma unroll
    for (int j = 0; j < 8; ++j) {
      float2 v = vv[j];
      switch (dd[j]) {
        case 0: ACC(0)
        case 1: ACC(1)
        case 2: ACC(2)
        case 3: ACC(3)
        case 4: ACC(4)
        case 5: ACC(5)
        case 6: ACC(6)
        case 7: ACC(7)
      }
    }
  }
#undef ACC

  // partials layout: float2 (s1,s2) at index (rg*D + d)*F + f  (f = feature).
  // This thread's f = h*512 + t*2 covers f, f+1 -> one float4 store.
  float4* __restrict__ p4 = (float4*)partials;
#pragma unroll
  for (int k = 0; k < D; ++k) {
    float4 w = make_float4(a1[k].x, a2[k].x, a1[k].y, a2[k].y);
    p4[(rg * D + k) * 512 + h * 256 + t] = w;
  }
}

// ---------------- kernel 2: reduce partials -> scale/shift ----------------
// grid = D*F/256 = 32 blocks. One thread per (d,f) pair.
__global__ __launch_bounds__(256) void k2_stats(
    const float* __restrict__ partials, const int* __restrict__ counts,
    const float* __restrict__ gamma, const float* __restrict__ beta,
    float* __restrict__ scale, float* __restrict__ shift) {
  const int p = blockIdx.x * 256 + threadIdx.x;  // (d,f) flat, 0..8191
  const int d = p >> 10;

  const float2* __restrict__ pp = (const float2*)partials + p;
  float s1 = 0.f, s2 = 0.f;
#pragma unroll 8
  for (int rg = 0; rg < RG; ++rg) {
    float2 v = pp[rg * (D * F)];
    s1 += v.x;
    s2 += v.y;
  }

  const float c = (float)counts[d];
  const float cc = fmaxf(c, 1.f);
  const float mean = s1 / cc;
  const float var = s2 / cc - mean * mean;
  const float inv = rsqrtf(var + EPSV);
  float sc = gamma[p] * inv;
  float sh = beta[p] - mean * sc;
  if (c <= 1.f) {  // count==1: passthrough x; count==0: zero output
    sc = (c == 1.f) ? 1.f : 0.f;
    sh = 0.f;
  }
  scale[p] = sc;
  shift[p] = sh;
}

// ---------------- kernel 3: apply ----------------
// grid = N blocks, block = 256, one float4 per thread (256*4 = F).
__global__ __launch_bounds__(256) void k3_apply(
    const float* __restrict__ x, const int* __restrict__ y,
    const float* __restrict__ scale, const float* __restrict__ shift,
    float* __restrict__ out) {
  const int n = blockIdx.x;
  const int t = threadIdx.x;
  const int d = y[n];  // uniform -> s_load

  const float4 v = ((const float4*)x)[n * 256 + t];
  const float4 g = ((const float4*)scale)[d * 256 + t];
  const float4 b = ((const float4*)shift)[d * 256 + t];
  float4 o;
  o.x = fmaf(v.x, g.x, b.x);
  o.y = fmaf(v.y, g.y, b.y);
  o.z = fmaf(v.z, g.z, b.z);
  o.w = fmaf(v.w, g.w, b.w);
  ((float4*)out)[n * 256 + t] = o;
}

extern "C" void kernel_launch(void* const* d_in, const int* in_sizes, int n_in,
                              void* d_out, int out_size, void* d_ws, size_t ws_size,
                              hipStream_t stream) {
  const float* x = (const float*)d_in[0];
  const int* y = (const int*)d_in[1];
  const float* gamma = (const float*)d_in[2];
  const float* beta = (const float*)d_in[3];
  float* out = (float*)d_out;

  // ws layout (floats): [partials: RG*D*F*2 = 2097152][counts: 8 ints + pad][scale: 8192][shift: 8192]
  float* partials = (float*)d_ws;
  const size_t poff = (size_t)RG * D * F * 2;
  int* counts = (int*)(partials + poff);
  float* scale = partials + poff + 64;   // 16B-aligned
  float* shift = scale + D * F;

  hipMemsetAsync(counts, 0, D * sizeof(int), stream);
  k1_partials<<<RG * 2, 256, 0, stream>>>(x, y, partials, counts);
  k2_stats<<<(D * F) / 256, 256, 0, stream>>>(partials, counts, gamma, beta, scale, shift);
  k3_apply<<<N, 256, 0, stream>>>(x, y, scale, shift, out);
}

// Round 2
// 148.978 us; speedup vs baseline: 1.0093x; 1.0093x over previous
//
#include <hip/hip_runtime.h>

// DSBatchNorm: per-domain batch stats + affine. N=16384 rows, F=1024 feats, D=8 domains.
// Pass 1 (k1): per-(rowgroup, domain, feature) partial s1/s2 in registers -> ws. grid=512
//              (2 blocks/CU) for latency hiding; uniform-y switch keeps accumulate scalar-branched.
// Pass 2 (k2): reduce 256 partials, fold count edge cases into scale/shift (branch-free pass 3).
// Pass 3 (k3): out = x*scale[y] + shift[y]; 8 rows/block, fully unrolled for MLP.

#define EPSV 1e-5f
constexpr int N = 16384;
constexpr int F = 1024;
constexpr int D = 8;
constexpr int ROWS_PER_BLOCK = 64;   // was 128: halve rows -> 2x blocks -> 2 blocks/CU
constexpr int RG = N / ROWS_PER_BLOCK; // 256 row-groups

// ---------------- kernel 1: partial sums ----------------
// grid = RG*2 (2 column halves), block = 256. Each thread owns 2 consecutive
// floats (float2) of one half-row. acc[8] per-domain in registers.
// y[n] address is uniform (block/loop indices only) -> s_load + uniform branch.
__global__ __launch_bounds__(256) void k1_partials(
    const float* __restrict__ x, const int* __restrict__ y,
    float* __restrict__ partials, int* __restrict__ counts) {
  const int t = threadIdx.x;
  const int rg = blockIdx.x >> 1;
  const int h = blockIdx.x & 1;

  __shared__ int hist[D];
  if (t < D) hist[t] = 0;
  __syncthreads();
  if (h == 0 && t < ROWS_PER_BLOCK) {
    int d = y[rg * ROWS_PER_BLOCK + t];
    atomicAdd(&hist[d], 1);
  }
  __syncthreads();
  if (h == 0 && t < D) atomicAdd(&counts[t], hist[t]);

  float2 a1[D], a2[D];
#pragma unroll
  for (int k = 0; k < D; ++k) {
    a1[k] = make_float2(0.f, 0.f);
    a2[k] = make_float2(0.f, 0.f);
  }

  const float2* __restrict__ x2 = (const float2*)x;
  const int col2 = h * 256 + t;  // float2 column index, 0..511
  const int row0 = rg * ROWS_PER_BLOCK;

#define ACC(K)                            \
  a1[K].x += v.x;                         \
  a1[K].y += v.y;                         \
  a2[K].x = fmaf(v.x, v.x, a2[K].x);      \
  a2[K].y = fmaf(v.y, v.y, a2[K].y);      \
  break;

  for (int r = 0; r < ROWS_PER_BLOCK; r += 8) {
    const int n = row0 + r;
    int dd[8];
    float2 vv[8];
#pragma unroll
    for (int j = 0; j < 8; ++j) dd[j] = y[n + j];        // uniform -> SGPR
#pragma unroll
    for (int j = 0; j < 8; ++j) vv[j] = x2[(n + j) * 512 + col2];  // 8 loads in flight
#pragma unroll
    for (int j = 0; j < 8; ++j) {
      float2 v = vv[j];
      switch (dd[j]) {
        case 0: ACC(0)
        case 1: ACC(1)
        case 2: ACC(2)
        case 3: ACC(3)
        case 4: ACC(4)
        case 5: ACC(5)
        case 6: ACC(6)
        case 7: ACC(7)
      }
    }
  }
#undef ACC

  // partials layout: float2 (s1,s2) at index (rg*D + d)*F + f  (f = feature).
  // This thread's f = h*512 + t*2 covers f, f+1 -> one float4 store.
  float4* __restrict__ p4 = (float4*)partials;
#pragma unroll
  for (int k = 0; k < D; ++k) {
    float4 w = make_float4(a1[k].x, a2[k].x, a1[k].y, a2[k].y);
    p4[(rg * D + k) * 512 + h * 256 + t] = w;
  }
}

// ---------------- kernel 2: reduce partials -> scale/shift ----------------
// grid = D*F/256 = 32 blocks. One thread per (d,f) pair.
__global__ __launch_bounds__(256) void k2_stats(
    const float* __restrict__ partials, const int* __restrict__ counts,
    const float* __restrict__ gamma, const float* __restrict__ beta,
    float* __restrict__ scale, float* __restrict__ shift) {
  const int p = blockIdx.x * 256 + threadIdx.x;  // (d,f) flat, 0..8191
  const int d = p >> 10;

  const float2* __restrict__ pp = (const float2*)partials + p;
  float s1 = 0.f, s2 = 0.f;
#pragma unroll 8
  for (int rg = 0; rg < RG; ++rg) {
    float2 v = pp[rg * (D * F)];
    s1 += v.x;
    s2 += v.y;
  }

  const float c = (float)counts[d];
  const float cc = fmaxf(c, 1.f);
  const float mean = s1 / cc;
  const float var = s2 / cc - mean * mean;
  const float inv = rsqrtf(var + EPSV);
  float sc = gamma[p] * inv;
  float sh = beta[p] - mean * sc;
  if (c <= 1.f) {  // count==1: passthrough x; count==0: zero output
    sc = (c == 1.f) ? 1.f : 0.f;
    sh = 0.f;
  }
  scale[p] = sc;
  shift[p] = sh;
}

// ---------------- kernel 3: apply ----------------
// grid = N/8 = 2048 blocks, block = 256; 8 rows/block, one float4 per thread
// per row (256*4 = F). All 8 rows unrolled: 24 loads in flight per thread.
__global__ __launch_bounds__(256) void k3_apply(
    const float* __restrict__ x, const int* __restrict__ y,
    const float* __restrict__ scale, const float* __restrict__ shift,
    float* __restrict__ out) {
  const int t = threadIdx.x;
  const int n0 = blockIdx.x * 8;

  int dd[8];
#pragma unroll
  for (int j = 0; j < 8; ++j) dd[j] = y[n0 + j];  // uniform -> s_load

#pragma unroll
  for (int j = 0; j < 8; ++j) {
    const int n = n0 + j;
    const float4 v = ((const float4*)x)[n * 256 + t];
    const float4 g = ((const float4*)scale)[dd[j] * 256 + t];
    const float4 b = ((const float4*)shift)[dd[j] * 256 + t];
    float4 o;
    o.x = fmaf(v.x, g.x, b.x);
    o.y = fmaf(v.y, g.y, b.y);
    o.z = fmaf(v.z, g.z, b.z);
    o.w = fmaf(v.w, g.w, b.w);
    ((float4*)out)[n * 256 + t] = o;
  }
}

extern "C" void kernel_launch(void* const* d_in, const int* in_sizes, int n_in,
                              void* d_out, int out_size, void* d_ws, size_t ws_size,
                              hipStream_t stream) {
  const float* x = (const float*)d_in[0];
  const int* y = (const int*)d_in[1];
  const float* gamma = (const float*)d_in[2];
  const float* beta = (const float*)d_in[3];
  float* out = (float*)d_out;

  // ws layout (floats): [partials: RG*D*F*2 = 4194304][counts: 8 ints + pad][scale: 8192][shift: 8192]
  float* partials = (float*)d_ws;
  const size_t poff = (size_t)RG * D * F * 2;
  int* counts = (int*)(partials + poff);
  float* scale = partials + poff + 64;   // 16B-aligned
  float* shift = scale + D * F;

  hipMemsetAsync(counts, 0, D * sizeof(int), stream);
  k1_partials<<<RG * 2, 256, 0, stream>>>(x, y, partials, counts);
  k2_stats<<<(D * F) / 256, 256, 0, stream>>>(partials, counts, gamma, beta, scale, shift);
  k3_apply<<<N / 8, 256, 0, stream>>>(x, y, scale, shift, out);
}

// Round 3
// 138.241 us; speedup vs baseline: 1.0877x; 1.0777x over previous
//
#include <hip/hip_runtime.h>

// DSBatchNorm: per-domain batch stats + affine. N=16384 rows, F=1024 feats, D=8 domains.
// k1 : per-(rowgroup, domain, feature) partial s1/s2 in registers -> ws (512 blocks).
//      Per-rowgroup y-histograms to ws (no global atomics, no memset needed).
// k2a: reduce 256 rowgroup-partials -> 16 (256 blocks, full BW; fixes the 32-block
//      760 GB/s bottleneck that made old k2 ~22us).
// k2b: 16 -> 1 + counts + fold edge cases into scale/shift (32 blocks, L2-hot).
// k3 : out = x*scale[y] + shift[y], branch-free (2048 blocks, 8 rows each).

#define EPSV 1e-5f
constexpr int N = 16384;
constexpr int F = 1024;
constexpr int D = 8;
constexpr int ROWS_PER_BLOCK = 64;
constexpr int RG = N / ROWS_PER_BLOCK;  // 256 row-groups

// ---------------- kernel 1: partial sums ----------------
// grid = RG*2 (2 column halves), block = 256. Each thread owns 2 consecutive
// floats (float2) of one half-row; acc[8] per-domain in registers.
// y[n] address is uniform (block/loop indices only) -> s_load + uniform branch.
__global__ __launch_bounds__(256) void k1_partials(
    const float* __restrict__ x, const int* __restrict__ y,
    float* __restrict__ partials, int* __restrict__ cnt_parts) {
  const int t = threadIdx.x;
  const int rg = blockIdx.x >> 1;
  const int h = blockIdx.x & 1;

  __shared__ int hist[D];
  if (t < D) hist[t] = 0;
  __syncthreads();
  if (h == 0 && t < ROWS_PER_BLOCK) {
    int d = y[rg * ROWS_PER_BLOCK + t];
    atomicAdd(&hist[d], 1);
  }
  __syncthreads();
  if (h == 0 && t < D) cnt_parts[rg * D + t] = hist[t];  // plain store, one writer per rg

  float2 a1[D], a2[D];
#pragma unroll
  for (int k = 0; k < D; ++k) {
    a1[k] = make_float2(0.f, 0.f);
    a2[k] = make_float2(0.f, 0.f);
  }

  const float2* __restrict__ x2 = (const float2*)x;
  const int col2 = h * 256 + t;  // float2 column index, 0..511
  const int row0 = rg * ROWS_PER_BLOCK;

#define ACC(K)                            \
  a1[K].x += v.x;                         \
  a1[K].y += v.y;                         \
  a2[K].x = fmaf(v.x, v.x, a2[K].x);      \
  a2[K].y = fmaf(v.y, v.y, a2[K].y);      \
  break;

  for (int r = 0; r < ROWS_PER_BLOCK; r += 8) {
    const int n = row0 + r;
    int dd[8];
    float2 vv[8];
#pragma unroll
    for (int j = 0; j < 8; ++j) dd[j] = y[n + j];        // uniform -> SGPR
#pragma unroll
    for (int j = 0; j < 8; ++j) vv[j] = x2[(n + j) * 512 + col2];  // 8 loads in flight
#pragma unroll
    for (int j = 0; j < 8; ++j) {
      float2 v = vv[j];
      switch (dd[j]) {
        case 0: ACC(0)
        case 1: ACC(1)
        case 2: ACC(2)
        case 3: ACC(3)
        case 4: ACC(4)
        case 5: ACC(5)
        case 6: ACC(6)
        case 7: ACC(7)
      }
    }
  }
#undef ACC

  // partials layout: float4 (s1.x,s2.x,s1.y,s2.y) at float4-index (rg*D+d)*512 + c2.
  float4* __restrict__ p4 = (float4*)partials;
#pragma unroll
  for (int k = 0; k < D; ++k) {
    float4 w = make_float4(a1[k].x, a2[k].x, a1[k].y, a2[k].y);
    p4[(rg * D + k) * 512 + h * 256 + t] = w;
  }
}

// ---------------- kernel 2a: 256 rowgroup-partials -> 16 ----------------
// grid = 256 blocks (16 rg-groups x 16 slice-quarters), block = 256.
// Each thread: 16 float4 loads (1KB/wave contiguous) + 1 float4 store.
__global__ __launch_bounds__(256) void k2a_reduce(
    const float4* __restrict__ partials, float4* __restrict__ out16) {
  const int rgg = blockIdx.x >> 4;                 // 0..15
  const int q = blockIdx.x & 15;                   // 0..15
  const int idx = q * 256 + threadIdx.x;           // 0..4095 (= d*512 + c2)
  const float4* __restrict__ p = partials + (size_t)(rgg * 16) * 4096 + idx;
  float4 s = make_float4(0.f, 0.f, 0.f, 0.f);
#pragma unroll
  for (int i = 0; i < 16; ++i) {
    float4 v = p[i * 4096];
    s.x += v.x; s.y += v.y; s.z += v.z; s.w += v.w;
  }
  out16[rgg * 4096 + idx] = s;
}

// ---------------- kernel 2b: finish stats -> scale/shift ----------------
// grid = 32 blocks, block = 256; one thread per (d,f). Data is 1 MiB, L2/L3-hot.
__global__ __launch_bounds__(256) void k2b_stats(
    const float* __restrict__ out16, const int* __restrict__ cnt_parts,
    const float* __restrict__ gamma, const float* __restrict__ beta,
    float* __restrict__ scale, float* __restrict__ shift) {
  const int t = threadIdx.x;
  const int p = blockIdx.x * 256 + t;  // (d,f) flat, 0..8191
  const int d = p >> 10;               // uniform per block (256 | 1024)

  // counts: reduce the 256 per-rowgroup histograms for domain d.
  __shared__ int sc[256];
  sc[t] = cnt_parts[t * D + d];
  __syncthreads();
  for (int s = 128; s > 0; s >>= 1) {
    if (t < s) sc[t] += sc[t + s];
    __syncthreads();
  }
  const float c = (float)sc[0];

  const float2* __restrict__ pp = (const float2*)out16 + p;
  float s1 = 0.f, s2 = 0.f;
#pragma unroll
  for (int i = 0; i < 16; ++i) {
    float2 v = pp[i * (D * F)];
    s1 += v.x;
    s2 += v.y;
  }

  const float cc = fmaxf(c, 1.f);
  const float mean = s1 / cc;
  const float var = s2 / cc - mean * mean;
  const float inv = rsqrtf(var + EPSV);
  float scv = gamma[p] * inv;
  float shv = beta[p] - mean * scv;
  if (c <= 1.f) {  // count==1: passthrough x; count==0: zero output
    scv = (c == 1.f) ? 1.f : 0.f;
    shv = 0.f;
  }
  scale[p] = scv;
  shift[p] = shv;
}

// ---------------- kernel 3: apply ----------------
// grid = N/8 = 2048 blocks, block = 256; 8 rows/block, one float4 per thread
// per row (256*4 = F). All 8 rows unrolled: 24 loads in flight per thread.
__global__ __launch_bounds__(256) void k3_apply(
    const float* __restrict__ x, const int* __restrict__ y,
    const float* __restrict__ scale, const float* __restrict__ shift,
    float* __restrict__ out) {
  const int t = threadIdx.x;
  const int n0 = blockIdx.x * 8;

  int dd[8];
#pragma unroll
  for (int j = 0; j < 8; ++j) dd[j] = y[n0 + j];  // uniform -> s_load

#pragma unroll
  for (int j = 0; j < 8; ++j) {
    const int n = n0 + j;
    const float4 v = ((const float4*)x)[n * 256 + t];
    const float4 g = ((const float4*)scale)[dd[j] * 256 + t];
    const float4 b = ((const float4*)shift)[dd[j] * 256 + t];
    float4 o;
    o.x = fmaf(v.x, g.x, b.x);
    o.y = fmaf(v.y, g.y, b.y);
    o.z = fmaf(v.z, g.z, b.z);
    o.w = fmaf(v.w, g.w, b.w);
    ((float4*)out)[n * 256 + t] = o;
  }
}

extern "C" void kernel_launch(void* const* d_in, const int* in_sizes, int n_in,
                              void* d_out, int out_size, void* d_ws, size_t ws_size,
                              hipStream_t stream) {
  const float* x = (const float*)d_in[0];
  const int* y = (const int*)d_in[1];
  const float* gamma = (const float*)d_in[2];
  const float* beta = (const float*)d_in[3];
  float* out = (float*)d_out;

  // ws layout (floats):
  //   partials : RG*D*F*2            = 4,194,304  (16 MiB)
  //   out16    : 16*D*F*2            =   262,144  (1 MiB)
  //   cnt_parts: RG*D ints           =     2,048
  //   scale    : D*F                 =     8,192
  //   shift    : D*F                 =     8,192
  float* partials = (float*)d_ws;
  float* out16 = partials + (size_t)RG * D * F * 2;
  int* cnt_parts = (int*)(out16 + 16 * D * F * 2);
  float* scale = (float*)(cnt_parts + RG * D);
  float* shift = scale + D * F;

  k1_partials<<<RG * 2, 256, 0, stream>>>(x, y, partials, cnt_parts);
  k2a_reduce<<<256, 256, 0, stream>>>((const float4*)partials, (float4*)out16);
  k2b_stats<<<32, 256, 0, stream>>>(out16, cnt_parts, gamma, beta, scale, shift);
  k3_apply<<<N / 8, 256, 0, stream>>>(x, y, scale, shift, out);
}

// Round 4
// 136.140 us; speedup vs baseline: 1.1045x; 1.0154x over previous
//
#include <hip/hip_runtime.h>

// DSBatchNorm: per-domain batch stats + affine. N=16384 rows, F=1024 feats, D=8 domains.
// k1: per-(rowgroup, domain, feature) partial s1/s2 in registers -> ws (512 blocks).
//     Per-rowgroup y-histograms to ws (no global atomics, no memset).
// k2: single-kernel 256->1 reduction (256 blocks). Lanes own consecutive (d,f)
//     pairs -> rowgroup-axis reads are 256B-contiguous per half-wave = coalesced.
//     Counts + edge cases folded into scale/shift (branch-free pass 3).
// k3: out = x*scale[y] + shift[y] (2048 blocks, 8 rows each, fully unrolled).

#define EPSV 1e-5f
constexpr int N = 16384;
constexpr int F = 1024;
constexpr int D = 8;
constexpr int ROWS_PER_BLOCK = 64;
constexpr int RG = N / ROWS_PER_BLOCK;  // 256 row-groups

// ---------------- kernel 1: partial sums ----------------
// grid = RG*2 (2 column halves), block = 256. Each thread owns 2 consecutive
// floats (float2) of one half-row; acc[8] per-domain in registers.
// y[n] address is uniform (block/loop indices only) -> s_load + uniform branch.
__global__ __launch_bounds__(256) void k1_partials(
    const float* __restrict__ x, const int* __restrict__ y,
    float* __restrict__ partials, int* __restrict__ cnt_parts) {
  const int t = threadIdx.x;
  const int rg = blockIdx.x >> 1;
  const int h = blockIdx.x & 1;

  __shared__ int hist[D];
  if (t < D) hist[t] = 0;
  __syncthreads();
  if (h == 0 && t < ROWS_PER_BLOCK) {
    int d = y[rg * ROWS_PER_BLOCK + t];
    atomicAdd(&hist[d], 1);
  }
  __syncthreads();
  if (h == 0 && t < D) cnt_parts[rg * D + t] = hist[t];  // one writer per rg

  float2 a1[D], a2[D];
#pragma unroll
  for (int k = 0; k < D; ++k) {
    a1[k] = make_float2(0.f, 0.f);
    a2[k] = make_float2(0.f, 0.f);
  }

  const float2* __restrict__ x2 = (const float2*)x;
  const int col2 = h * 256 + t;  // float2 column index, 0..511
  const int row0 = rg * ROWS_PER_BLOCK;

#define ACC(K)                            \
  a1[K].x += v.x;                         \
  a1[K].y += v.y;                         \
  a2[K].x = fmaf(v.x, v.x, a2[K].x);      \
  a2[K].y = fmaf(v.y, v.y, a2[K].y);      \
  break;

  for (int r = 0; r < ROWS_PER_BLOCK; r += 8) {
    const int n = row0 + r;
    int dd[8];
    float2 vv[8];
#pragma unroll
    for (int j = 0; j < 8; ++j) dd[j] = y[n + j];        // uniform -> SGPR
#pragma unroll
    for (int j = 0; j < 8; ++j) vv[j] = x2[(n + j) * 512 + col2];  // 8 loads in flight
#pragma unroll
    for (int j = 0; j < 8; ++j) {
      float2 v = vv[j];
      switch (dd[j]) {
        case 0: ACC(0)
        case 1: ACC(1)
        case 2: ACC(2)
        case 3: ACC(3)
        case 4: ACC(4)
        case 5: ACC(5)
        case 6: ACC(6)
        case 7: ACC(7)
      }
    }
  }
#undef ACC

  // partials as float2: pp2[(rg*D + d)*1024 + f] = (s1[f], s2[f]).
  float4* __restrict__ p4 = (float4*)partials;
#pragma unroll
  for (int k = 0; k < D; ++k) {
    float4 w = make_float4(a1[k].x, a2[k].x, a1[k].y, a2[k].y);
    p4[(rg * D + k) * 512 + h * 256 + t] = w;
  }
}

// ---------------- kernel 2: full stats reduction -> scale/shift ----------------
// grid = 256 blocks, block = 256. Block b owns 32 consecutive (d,f) pairs
// (p = b*32 + (t&31); d uniform per block). Thread t reduces rg-chunk (t>>5):
// 32 float2 loads, half-wave reads are 256B contiguous. LDS finishes 8 chunks.
__global__ __launch_bounds__(256) void k2_stats(
    const float* __restrict__ partials, const int* __restrict__ cnt_parts,
    const float* __restrict__ gamma, const float* __restrict__ beta,
    float* __restrict__ scale, float* __restrict__ shift) {
  const int t = threadIdx.x;
  const int i = t & 31;        // pair within block
  const int ch = t >> 5;       // rg-chunk, 0..7
  const int p = blockIdx.x * 32 + i;  // (d,f) flat
  const int d = p >> 10;       // uniform per block (32 | 1024)

  // counts: 256 per-rowgroup histogram entries for domain d, tree-reduced.
  __shared__ int sc[256];
  sc[t] = cnt_parts[t * D + d];

  const float2* __restrict__ pp = (const float2*)partials;
  float s1 = 0.f, s2 = 0.f;
#pragma unroll 8
  for (int r = 0; r < 32; ++r) {
    const int rg = ch * 32 + r;
    float2 v = pp[(size_t)rg * (D * F) + p];
    s1 += v.x;
    s2 += v.y;
  }

  __shared__ float sf[8][32][2];
  sf[ch][i][0] = s1;
  sf[ch][i][1] = s2;
  __syncthreads();
  for (int s = 128; s > 0; s >>= 1) {
    if (t < s) sc[t] += sc[t + s];
    __syncthreads();
  }

  if (t < 32) {
    float r1 = 0.f, r2 = 0.f;
#pragma unroll
    for (int c = 0; c < 8; ++c) {
      r1 += sf[c][t][0];
      r2 += sf[c][t][1];
    }
    const int pw = blockIdx.x * 32 + t;
    const float c = (float)sc[0];
    const float cc = fmaxf(c, 1.f);
    const float mean = r1 / cc;
    const float var = r2 / cc - mean * mean;
    const float inv = rsqrtf(var + EPSV);
    float scv = gamma[pw] * inv;
    float shv = beta[pw] - mean * scv;
    if (c <= 1.f) {  // count==1: passthrough x; count==0: zero output
      scv = (c == 1.f) ? 1.f : 0.f;
      shv = 0.f;
    }
    scale[pw] = scv;
    shift[pw] = shv;
  }
}

// ---------------- kernel 3: apply ----------------
// grid = N/8 = 2048 blocks, block = 256; 8 rows/block, one float4 per thread
// per row (256*4 = F). All 8 rows unrolled: 24 loads in flight per thread.
__global__ __launch_bounds__(256) void k3_apply(
    const float* __restrict__ x, const int* __restrict__ y,
    const float* __restrict__ scale, const float* __restrict__ shift,
    float* __restrict__ out) {
  const int t = threadIdx.x;
  const int n0 = blockIdx.x * 8;

  int dd[8];
#pragma unroll
  for (int j = 0; j < 8; ++j) dd[j] = y[n0 + j];  // uniform -> s_load

#pragma unroll
  for (int j = 0; j < 8; ++j) {
    const int n = n0 + j;
    const float4 v = ((const float4*)x)[n * 256 + t];
    const float4 g = ((const float4*)scale)[dd[j] * 256 + t];
    const float4 b = ((const float4*)shift)[dd[j] * 256 + t];
    float4 o;
    o.x = fmaf(v.x, g.x, b.x);
    o.y = fmaf(v.y, g.y, b.y);
    o.z = fmaf(v.z, g.z, b.z);
    o.w = fmaf(v.w, g.w, b.w);
    ((float4*)out)[n * 256 + t] = o;
  }
}

extern "C" void kernel_launch(void* const* d_in, const int* in_sizes, int n_in,
                              void* d_out, int out_size, void* d_ws, size_t ws_size,
                              hipStream_t stream) {
  const float* x = (const float*)d_in[0];
  const int* y = (const int*)d_in[1];
  const float* gamma = (const float*)d_in[2];
  const float* beta = (const float*)d_in[3];
  float* out = (float*)d_out;

  // ws layout (floats):
  //   partials : RG*D*F*2 = 4,194,304  (16 MiB)
  //   cnt_parts: RG*D ints =    2,048
  //   scale    : D*F       =    8,192
  //   shift    : D*F       =    8,192
  float* partials = (float*)d_ws;
  int* cnt_parts = (int*)(partials + (size_t)RG * D * F * 2);
  float* scale = (float*)(cnt_parts + RG * D);
  float* shift = scale + D * F;

  k1_partials<<<RG * 2, 256, 0, stream>>>(x, y, partials, cnt_parts);
  k2_stats<<<256, 256, 0, stream>>>(partials, cnt_parts, gamma, beta, scale, shift);
  k3_apply<<<N / 8, 256, 0, stream>>>(x, y, scale, shift, out);
}